// Round 4
// baseline (532.942 us; speedup 1.0000x reference)
//
#include <hip/hip_runtime.h>
#include <hip/hip_bf16.h>
#include <math.h>

#define S_LEN 2048
#define HID   4096
#define NQKV  6144
#define NHEAD 32
#define NKVH  8
#define HDIM  128

typedef __attribute__((ext_vector_type(8))) short short8;
typedef __attribute__((ext_vector_type(4))) short short4v;
typedef __attribute__((ext_vector_type(4))) float f32x4;

__device__ __forceinline__ unsigned short f2bf(float f) {
    union { float f; unsigned u; } v; v.f = f;
    unsigned r = v.u + 0x7fffu + ((v.u >> 16) & 1u);
    return (unsigned short)(r >> 16);
}

// ---------------- fp32 -> bf16 convert ----------------
__global__ __launch_bounds__(256)
void cvt_kernel(const float* __restrict__ in, unsigned short* __restrict__ out, int n) {
    int idx = (blockIdx.x * 256 + threadIdx.x) * 4;
    int stride = gridDim.x * 256 * 4;
    for (; idx < n; idx += stride) {
        float4 v = *(const float4*)(in + idx);
        ushort4 o;
        o.x = f2bf(v.x); o.y = f2bf(v.y); o.z = f2bf(v.z); o.w = f2bf(v.w);
        *(ushort4*)(out + idx) = o;
    }
}

// ---------------- FWHT over 4096, * su, * 1/4096, -> bf16 ----------------
__global__ __launch_bounds__(256)
void fwht_kernel(const float* __restrict__ in, const float* __restrict__ su,
                 unsigned short* __restrict__ out) {
    __shared__ float buf[HID];
    const float* src = in + (size_t)blockIdx.x * HID;
    for (int i = threadIdx.x; i < HID; i += 256) buf[i] = src[i] * su[i];
    __syncthreads();
    int lg = 0;
    for (int h = 1; h < HID; h <<= 1, ++lg) {
        for (int p = threadIdx.x; p < HID / 2; p += 256) {
            int j  = p & (h - 1);
            int i0 = ((p >> lg) << (lg + 1)) | j;
            int i1 = i0 + h;
            float a = buf[i0], b = buf[i1];
            buf[i0] = a + b;
            buf[i1] = a - b;
        }
        __syncthreads();
    }
    unsigned short* dst = out + (size_t)blockIdx.x * HID;
    const float norm = 1.0f / 4096.0f;   // (1/sqrt(4096)) * (1/SCALE)
    for (int i = threadIdx.x; i < HID; i += 256) dst[i] = f2bf(buf[i] * norm);
}

// ---------------- phase-split bf16 GEMM (T2+T3+T4+T5) ----------------
// C[m][n] = (sum_k A[m][k]*B[n][k]) * scale[n] * 64
// MFR=8: BM=256 (2Mx4N waves, 128x64/wave); MFR=4: BM=128. BN=256, BK=64.
// LDS tiles [rows][64] bf16, byte-XOR swizzle ^((row&7)<<4) on both sides
// (linear gload_lds dest + inverse-swizzled global source). Counted vmcnt:
// loads for tile t+1 stay in flight during tile t's compute; drained one
// tile ahead, never vmcnt(0) mid-loop.
template<int MFR>
__global__ __launch_bounds__(512, 2)
void gemm_p(const unsigned short* __restrict__ A, const unsigned short* __restrict__ B,
            const float* __restrict__ scale, float* __restrict__ C,
            int M, int N, int K) {
    constexpr int BM  = MFR * 32;
    constexpr int LPA = BM / 64;       // A staging chunks per thread per tile
    constexpr int MQ  = MFR / 4;       // m-frags per phase
    __shared__ __attribute__((aligned(16))) unsigned short As[2][BM * 64];
    __shared__ __attribute__((aligned(16))) unsigned short Bs[2][256 * 64];
    const int bn = blockIdx.x, bm = blockIdx.y;
    const int tid = threadIdx.x;
    const int wv = tid >> 6, lane = tid & 63;
    const int wr = wv >> 2, wc = wv & 3;
    const int lr = lane & 15, lgp = lane >> 4;

    f32x4 acc[MFR][4] = {};

    const unsigned short* Abase = A + (size_t)(bm * BM) * K;
    const unsigned short* Bbase = B + (size_t)(bn * 256) * K;

    auto stage = [&](int buf, int kt) {
#pragma unroll
        for (int c = 0; c < LPA; ++c) {
            int o = (c * 512 + tid) * 16;                      // linear LDS byte offset
            int row = o >> 7;
            int col = ((o & 127) ^ ((row & 7) << 4)) >> 1;     // inverse-swizzled source
            __builtin_amdgcn_global_load_lds(
                (const __attribute__((address_space(1))) void*)(Abase + (size_t)row * K + kt * 64 + col),
                (__attribute__((address_space(3))) void*)&As[buf][o >> 1], 16, 0, 0);
        }
#pragma unroll
        for (int c = 0; c < 4; ++c) {
            int o = (c * 512 + tid) * 16;
            int row = o >> 7;
            int col = ((o & 127) ^ ((row & 7) << 4)) >> 1;
            __builtin_amdgcn_global_load_lds(
                (const __attribute__((address_space(1))) void*)(Bbase + (size_t)row * K + kt * 64 + col),
                (__attribute__((address_space(3))) void*)&Bs[buf][o >> 1], 16, 0, 0);
        }
    };

    const int NT = K >> 6;
    stage(0, 0);
    stage(1, 1);
    if constexpr (MFR == 8) asm volatile("s_waitcnt vmcnt(8)" ::: "memory");
    else                    asm volatile("s_waitcnt vmcnt(6)" ::: "memory");
    __builtin_amdgcn_s_barrier();

    for (int t = 0; t < NT; ++t) {
        const int cur = t & 1;
        short8 bfrag[4][2];
#pragma unroll
        for (int q = 0; q < 4; ++q) {
            if (q == 0) {
#pragma unroll
                for (int n2 = 0; n2 < 4; ++n2)
#pragma unroll
                    for (int kk = 0; kk < 2; ++kk) {
                        int row = wc * 64 + n2 * 16 + lr;
                        bfrag[n2][kk] = *(const short8*)&Bs[cur][((row * 128 + kk * 64 + lgp * 16) ^ ((row & 7) << 4)) >> 1];
                    }
            }
            short8 afrag[MQ][2];
#pragma unroll
            for (int m = 0; m < MQ; ++m)
#pragma unroll
                for (int kk = 0; kk < 2; ++kk) {
                    int row = wr * (MFR * 16) + (q * MQ + m) * 16 + lr;
                    afrag[m][kk] = *(const short8*)&As[cur][((row * 128 + kk * 64 + lgp * 16) ^ ((row & 7) << 4)) >> 1];
                }
            __builtin_amdgcn_s_barrier();
            asm volatile("s_waitcnt lgkmcnt(0)" ::: "memory");
            __builtin_amdgcn_sched_barrier(0);
            __builtin_amdgcn_s_setprio(1);
#pragma unroll
            for (int m = 0; m < MQ; ++m)
#pragma unroll
                for (int n2 = 0; n2 < 4; ++n2)
#pragma unroll
                    for (int kk = 0; kk < 2; ++kk)
                        acc[q * MQ + m][n2] = __builtin_amdgcn_mfma_f32_16x16x32_bf16(
                            afrag[m][kk], bfrag[n2][kk], acc[q * MQ + m][n2], 0, 0, 0);
            __builtin_amdgcn_s_setprio(0);
            __builtin_amdgcn_s_barrier();
        }
        // boundary: slot `cur` is free; keep next tile's loads in flight (counted)
        if (t + 2 < NT) {
            stage(cur, t + 2);
            if constexpr (MFR == 8) asm volatile("s_waitcnt vmcnt(8)" ::: "memory");
            else                    asm volatile("s_waitcnt vmcnt(6)" ::: "memory");
        } else if (t + 2 == NT) {
            asm volatile("s_waitcnt vmcnt(0)" ::: "memory");
        }
        __builtin_amdgcn_s_barrier();
    }

#pragma unroll
    for (int n2 = 0; n2 < 4; ++n2) {
        int gn = bn * 256 + wc * 64 + n2 * 16 + lr;
        float sc = scale[gn] * 64.0f;
#pragma unroll
        for (int m2 = 0; m2 < MFR; ++m2) {
            int gm0 = bm * BM + wr * (MFR * 16) + m2 * 16 + lgp * 4;
#pragma unroll
            for (int i = 0; i < 4; ++i)
                C[(size_t)(gm0 + i) * N + gn] = acc[m2][n2][i] * sc;
        }
    }
}

// ---------------- RoPE + relayout to head-major bf16 Q/K/V ----------------
// Q is pre-scaled by 1/sqrt(HDIM) so attention skips the softmax scale.
__global__ __launch_bounds__(256)
void rope_kernel(const float* __restrict__ qkv, const int* __restrict__ pos,
                 unsigned short* __restrict__ Qb, unsigned short* __restrict__ Kb,
                 unsigned short* __restrict__ Vb) {
    const int s = blockIdx.x;
    const float p = (float)pos[s];
    const float* row = qkv + (size_t)s * NQKV;
    const float sm = 0.08838834764831845f;   // 1/sqrt(128)
    for (int idx = threadIdx.x; idx < NQKV; idx += 256) {
        float v = row[idx];
        if (idx < HID + NKVH * HDIM) {      // q or k -> RoPE
            int base = (idx < HID) ? 0 : HID;
            int rel = idx - base;
            int h = rel >> 7, d = rel & 127;
            int j = d & 63;
            float invf = expf((float)j * (-13.122363377404329f / 64.0f)); // theta^(-2j/128)
            float ang = p * invf;
            float sn, cs;
            sincosf(ang, &sn, &cs);
            float other = (d < 64) ? -row[base + h * 128 + d + 64]
                                   :  row[base + h * 128 + d - 64];
            float r = v * cs + other * sn;
            if (idx < HID) Qb[((size_t)h * S_LEN + s) * HDIM + d] = f2bf(r * sm);
            else           Kb[((size_t)h * S_LEN + s) * HDIM + d] = f2bf(r);
        } else {                             // v passthrough
            int rel = idx - (HID + NKVH * HDIM);
            int h = rel >> 7, d = rel & 127;
            Vb[((size_t)h * S_LEN + s) * HDIM + d] = f2bf(v);
        }
    }
}

// ---------------- causal GQA flash attention (swapped QK^T, in-reg softmax) ----------------
// grid (32, 32): block x -> q-tile (31-x) (longest dispatched first).
// LDS 48KB (K dbuf + single V buffer) -> 3 blocks/CU. V staged via regs
// (regs are the second buffer); vcur reloaded in place after the scatter.
__global__ __launch_bounds__(256)
void attn_kernel(const unsigned short* __restrict__ Q, const unsigned short* __restrict__ K,
                 const unsigned short* __restrict__ V, float* __restrict__ O) {
    const int qt = 31 - (int)blockIdx.x;
    const int h  = blockIdx.y;
    const int kvh = h >> 2;
    const int tid = threadIdx.x, wv = tid >> 6, lane = tid & 63;
    const int lr = lane & 15, lgp = lane >> 4;

    __shared__ __attribute__((aligned(16))) unsigned short Ks[2][64 * 128];
    __shared__ __attribute__((aligned(16))) unsigned short Vt[128 * 64];

    int koff[4];
#pragma unroll
    for (int j = 0; j < 4; ++j) {
        int a = (wv * 4 + j) * 512 + lane * 8;
        koff[j] = a ^ (((a >> 7) & 7) << 3);
    }
    const unsigned short* Kg = K + (size_t)kvh * S_LEN * HDIM;
    const unsigned short* Vg = V + (size_t)kvh * S_LEN * HDIM;

    auto stageK = [&](int buf, int kb) {
        const unsigned short* kg = Kg + (size_t)kb * 64 * HDIM;
#pragma unroll
        for (int j = 0; j < 4; ++j) {
            __builtin_amdgcn_global_load_lds(
                (const __attribute__((address_space(1))) void*)(kg + koff[j]),
                (__attribute__((address_space(3))) void*)&Ks[buf][(wv * 4 + j) * 512], 16, 0, 0);
        }
    };

    const int qg = qt * 64 + wv * 16 + lr;   // this lane's q row (column of S^T)

    short8 aq[4];
    {
        const unsigned short* qp = Q + ((size_t)h * S_LEN + qg) * HDIM + lgp * 8;
#pragma unroll
        for (int kk = 0; kk < 4; ++kk) aq[kk] = *(const short8*)(qp + kk * 32);
    }

    f32x4 oacc[8] = {};
    float m_i = -3.0e38f, l_i = 0.f;

    short8 vcur[4];
    stageK(0, 0);
    {
        const unsigned short* vp = Vg + lane * HDIM + wv * 32;
#pragma unroll
        for (int r2 = 0; r2 < 4; ++r2) vcur[r2] = *(const short8*)(vp + r2 * 8);
    }

#pragma unroll 1
    for (int kb = 0; kb <= qt; ++kb) {
        const int cur = kb & 1;
        __syncthreads();   // b1: prev PV reads of Vt done; drains prefetches
        // scatter V regs -> transposed swizzled Vt ([d][kv], ^((d&7)<<3))
#pragma unroll
        for (int r2 = 0; r2 < 4; ++r2) {
#pragma unroll
            for (int e = 0; e < 8; ++e) {
                int d = wv * 32 + r2 * 8 + e;
                Vt[(d * 64 + lane) ^ ((d & 7) << 3)] = ((const unsigned short*)&vcur[r2])[e];
            }
        }
        __syncthreads();   // b2: scatter visible

        if (kb < qt) {     // next tile's loads fly during compute
            stageK(cur ^ 1, kb + 1);
            const unsigned short* vp = Vg + (size_t)(kb + 1) * 64 * HDIM + lane * HDIM + wv * 32;
#pragma unroll
            for (int r2 = 0; r2 < 4; ++r2) vcur[r2] = *(const short8*)(vp + r2 * 8);
        }

        __builtin_amdgcn_s_setprio(1);
        // QK^T swapped: sc[nt2] rows = kv (nt2*16 + 4*lgp + i), cols = q (lr)
        f32x4 sc[4];
#pragma unroll
        for (int nt2 = 0; nt2 < 4; ++nt2) {
            f32x4 a = {};
            const int krow = nt2 * 16 + lr;
            const int swz = (krow & 7) << 3;
#pragma unroll
            for (int kk = 0; kk < 4; ++kk) {
                short8 ak = *(const short8*)&Ks[cur][(krow * 128 + kk * 32 + lgp * 8) ^ swz];
                a = __builtin_amdgcn_mfma_f32_16x16x32_bf16(ak, aq[kk], a, 0, 0, 0);
            }
            sc[nt2] = a;
        }
        __builtin_amdgcn_s_setprio(0);

        if (kb == qt) {    // causal mask (Q pre-scaled, no sm mul needed)
#pragma unroll
            for (int nt2 = 0; nt2 < 4; ++nt2)
#pragma unroll
                for (int i = 0; i < 4; ++i) {
                    int kvg = kb * 64 + nt2 * 16 + 4 * lgp + i;
                    if (kvg > qg) sc[nt2][i] = -1.0e30f;
                }
        }

        // in-register online softmax for q = lr
        float vmax = fmaxf(fmaxf(fmaxf(sc[0][0], sc[0][1]), fmaxf(sc[0][2], sc[0][3])),
                           fmaxf(fmaxf(sc[1][0], sc[1][1]), fmaxf(sc[1][2], sc[1][3])));
        vmax = fmaxf(vmax, fmaxf(fmaxf(fmaxf(sc[2][0], sc[2][1]), fmaxf(sc[2][2], sc[2][3])),
                                 fmaxf(fmaxf(sc[3][0], sc[3][1]), fmaxf(sc[3][2], sc[3][3]))));
        vmax = fmaxf(vmax, __shfl_xor(vmax, 16));
        vmax = fmaxf(vmax, __shfl_xor(vmax, 32));
        float mn = fmaxf(m_i, vmax);
        float fe = __expf(m_i - mn);
        m_i = mn;
        l_i *= fe;
        float rs = 0.f;
#pragma unroll
        for (int nt2 = 0; nt2 < 4; ++nt2)
#pragma unroll
            for (int i = 0; i < 4; ++i) {
                float pv = __expf(sc[nt2][i] - mn);
                sc[nt2][i] = pv;
                rs += pv;
            }
        rs += __shfl_xor(rs, 16);
        rs += __shfl_xor(rs, 32);
        l_i += rs;

        // rescale oacc rows (row q = 4*lgp + i2; fe lives at lane with lr == that q)
        float feb[4];
#pragma unroll
        for (int i2 = 0; i2 < 4; ++i2) feb[i2] = __shfl(fe, 4 * lgp + i2);
#pragma unroll
        for (int t = 0; t < 8; ++t)
#pragma unroll
            for (int i2 = 0; i2 < 4; ++i2) oacc[t][i2] *= feb[i2];

        // P (A-operand, permuted-k): slot i<4 -> sc[2kk][i], slot i>=4 -> sc[2kk+1][i-4]
        short8 ap[2];
#pragma unroll
        for (int kk = 0; kk < 2; ++kk)
#pragma unroll
            for (int j = 0; j < 4; ++j) {
                ap[kk][j]     = (short)f2bf(sc[2 * kk][j]);
                ap[kk][4 + j] = (short)f2bf(sc[2 * kk + 1][j]);
            }

        // PV: B = V^T fragments from Vt with the SAME permuted-k convention
        __builtin_amdgcn_s_setprio(1);
#pragma unroll
        for (int t = 0; t < 8; ++t) {
            const int d = t * 16 + lr;
            const int swz = (d & 7) << 3;
            const int dbase = d * 64;
#pragma unroll
            for (int kk = 0; kk < 2; ++kk) {
                short4v lo = *(const short4v*)&Vt[(dbase + kk * 32 + lgp * 4) ^ swz];
                short4v hi = *(const short4v*)&Vt[(dbase + kk * 32 + 16 + lgp * 4) ^ swz];
                short8 bv;
                bv[0] = lo[0]; bv[1] = lo[1]; bv[2] = lo[2]; bv[3] = lo[3];
                bv[4] = hi[0]; bv[5] = hi[1]; bv[6] = hi[2]; bv[7] = hi[3];
                oacc[t] = __builtin_amdgcn_mfma_f32_16x16x32_bf16(ap[kk], bv, oacc[t], 0, 0, 0);
            }
        }
        __builtin_amdgcn_s_setprio(0);
    }

    // epilogue: O[q][d], q = qt*64 + wv*16 + 4*lgp + i2, d = t*16 + lr
    float invb[4];
    {
        float inv = 1.0f / l_i;
#pragma unroll
        for (int i2 = 0; i2 < 4; ++i2) invb[i2] = __shfl(inv, 4 * lgp + i2);
    }
    float* ob = O + (size_t)(qt * 64 + wv * 16 + 4 * lgp) * HID + h * HDIM + lr;
#pragma unroll
    for (int t = 0; t < 8; ++t)
#pragma unroll
        for (int i2 = 0; i2 < 4; ++i2)
            ob[(size_t)i2 * HID + t * 16] = oacc[t][i2] * invb[i2];
}

// ---------------- launch ----------------
extern "C" void kernel_launch(void* const* d_in, const int* in_sizes, int n_in,
                              void* d_out, int out_size, void* d_ws, size_t ws_size,
                              hipStream_t stream) {
    const float* hidden = (const float*)d_in[0];
    const int*   pos    = (const int*)d_in[1];
    const float* su_qkv = (const float*)d_in[2];
    const float* su_o   = (const float*)d_in[3];
    const float* ws_qkv = (const float*)d_in[4];
    const float* ws_o   = (const float*)d_in[5];
    const float* Wq     = (const float*)d_in[6];
    const float* Wk     = (const float*)d_in[7];
    const float* Wv     = (const float*)d_in[8];
    const float* Wo     = (const float*)d_in[9];
    float* out = (float*)d_out;

    char* ws = (char*)d_ws;
    unsigned short* Wcat = (unsigned short*)(ws);                        // [6144][4096] bf16
    unsigned short* Wob  = (unsigned short*)(ws + 50331648);             // [4096][4096] bf16
    unsigned short* xb   = (unsigned short*)(ws + 83886080);             // [2048][4096] bf16 (reused as y_in)
    float*          qkv  = (float*)(ws + 100663296);                     // [2048][6144] f32 (reused as attn_out)
    unsigned short* Qb   = (unsigned short*)(ws + 150994944);            // [32][2048][128] bf16
    unsigned short* Kb   = Qb + (size_t)NHEAD * S_LEN * HDIM;
    unsigned short* Vb   = Kb + (size_t)NKVH * S_LEN * HDIM;
    float* attn_out = qkv;

    cvt_kernel<<<1024, 256, 0, stream>>>(Wq, Wcat, HID * HID);
    cvt_kernel<<<256, 256, 0, stream>>>(Wk, Wcat + (size_t)HID * HID, NKVH * HDIM * HID);
    cvt_kernel<<<256, 256, 0, stream>>>(Wv, Wcat + (size_t)(HID + NKVH * HDIM) * HID, NKVH * HDIM * HID);
    cvt_kernel<<<1024, 256, 0, stream>>>(Wo, Wob, HID * HID);

    fwht_kernel<<<S_LEN, 256, 0, stream>>>(hidden, su_qkv, xb);
    gemm_p<8><<<dim3(NQKV / 256, S_LEN / 256), 512, 0, stream>>>(xb, Wcat, ws_qkv, qkv, S_LEN, NQKV, HID);
    rope_kernel<<<S_LEN, 256, 0, stream>>>(qkv, pos, Qb, Kb, Vb);
    attn_kernel<<<dim3(32, NHEAD), 256, 0, stream>>>(Qb, Kb, Vb, attn_out);
    fwht_kernel<<<S_LEN, 256, 0, stream>>>(attn_out, su_o, xb);
    gemm_p<4><<<dim3(HID / 256, S_LEN / 128), 512, 0, stream>>>(xb, Wob, ws_o, out, S_LEN, HID, HID);
}